// Round 6
// baseline (106.655 us; speedup 1.0000x reference)
//
#include <hip/hip_runtime.h>
#include <hip/hip_bf16.h>

// Problem constants (match reference)
#define MM 15   // max_peptide_size
#define RR 64   // aa_rep_size
#define PP 34   // pocket positions
#define FF 9    // filter size
#define AA 20   // alphabet size
#define OW (RR + FF - 1)   // 72 output width

// One block per sample b. 256 threads.
// Stage everything in LDS, compute s = adj @ pe, then convolve.
__global__ __launch_bounds__(256)
void peptide_pocket_conv_kernel(const float* __restrict__ pe,      // [B, M, R]
                                const int*   __restrict__ idx,     // [B, P]
                                const int*   __restrict__ adj,     // [B, P, M]
                                const float* __restrict__ kernels, // [A, F]
                                float*       __restrict__ out)     // [B, P, OW]
{
    const int b = blockIdx.x;
    const int t = threadIdx.x;

    __shared__ float s_pe[MM * RR];     // 960 f
    __shared__ float s_kern[AA * FF];   // 180 f
    __shared__ float s_adj[PP * MM];    // 510 f
    __shared__ int   s_idx[PP];
    __shared__ float s_s[PP][RR];       // 2176 f

    const float* peb  = pe  + (size_t)b * (MM * RR);
    const int*   adjb = adj + (size_t)b * (PP * MM);

    // Coalesced staging
    for (int i = t; i < MM * RR; i += 256) s_pe[i] = peb[i];
    for (int i = t; i < AA * FF; i += 256) s_kern[i] = kernels[i];
    for (int i = t; i < PP * MM; i += 256) s_adj[i] = (float)adjb[i];
    if (t < PP) s_idx[t] = idx[(size_t)b * PP + t];
    __syncthreads();

    // s[p][r] = sum_m adj[p][m] * pe[m][r]
    // i covers 34*64 = 2176 elements; within a 64-lane wave, p is constant
    // (i>>6) -> s_adj reads are broadcast (free), s_pe reads are stride-1.
    for (int i = t; i < PP * RR; i += 256) {
        const int p = i >> 6;
        const int r = i & 63;
        float acc = 0.0f;
        #pragma unroll
        for (int m = 0; m < MM; ++m)
            acc += s_adj[p * MM + m] * s_pe[m * RR + r];
        s_s[p][r] = acc;
    }
    __syncthreads();

    // out[p][o] = sum_{r in [max(0,o-F+1), min(R-1,o)]} s[p][r] * k[idx[p]][o-r]
    float* outb = out + (size_t)b * (PP * OW);
    for (int i = t; i < PP * OW; i += 256) {
        const int p = i / OW;
        const int o = i - p * OW;
        const float* kf = &s_kern[s_idx[p] * FF];
        int rlo = o - (FF - 1); if (rlo < 0) rlo = 0;
        int rhi = o;            if (rhi > RR - 1) rhi = RR - 1;
        float acc = 0.0f;
        for (int r = rlo; r <= rhi; ++r)
            acc += s_s[p][r] * kf[o - r];
        outb[i] = acc;
    }
}

extern "C" void kernel_launch(void* const* d_in, const int* in_sizes, int n_in,
                              void* d_out, int out_size, void* d_ws, size_t ws_size,
                              hipStream_t stream) {
    const float* pe      = (const float*)d_in[0]; // [B,M,R] f32
    const int*   idx     = (const int*)  d_in[1]; // [B,P]   i32
    const int*   adj     = (const int*)  d_in[2]; // [B,P,M] i32
    const float* kernels = (const float*)d_in[3]; // [A,F]   f32
    float*       out     = (float*)d_out;

    const int B = in_sizes[0] / (MM * RR);
    peptide_pocket_conv_kernel<<<B, 256, 0, stream>>>(pe, idx, adj, kernels, out);
}

// Round 7
// 78.855 us; speedup vs baseline: 1.3526x; 1.3526x over previous
//
#include <hip/hip_runtime.h>

// Problem constants
#define MM 15   // max_peptide_size
#define RR 64   // aa_rep_size
#define PP 34   // pocket positions
#define FF 9    // filter size
#define AA 20   // alphabet size
#define OW 72   // RR + FF - 1
#define SP 84   // padded s-row stride (floats): 16B-aligned float4 rows, bank-spread (84%32=20)
#define KS 12   // kernels row stride (floats): 16B-aligned
#define AJ 17   // adj-float row stride (bank-spread)

// One block per sample. 256 threads.
// s_pad[p][0..7]=0, s_pad[p][8+r]=s[p][r], s_pad[p][72..83]=0  -> fixed 9-tap conv, no branches.
__global__ __launch_bounds__(256)
void ppc_kernel(const float* __restrict__ pe,      // [B, M, R]
                const int*   __restrict__ idx,     // [B, P]
                const int*   __restrict__ adj,     // [B, P, M]
                const float* __restrict__ kernels, // [A, F]
                float*       __restrict__ out)     // [B, P, OW]
{
    const int b = blockIdx.x;
    const int t = threadIdx.x;

    __shared__ float s_pe[MM * RR];      // 960 f
    __shared__ float s_kern[AA * KS];    // 240 f (stride-12, pad 3)
    __shared__ float s_adjf[PP * AJ];    // 578 f (adj as 0.0/1.0 floats)
    __shared__ int   s_idx[PP];
    __shared__ float s_s[PP * SP];       // 2856 f = 11.4 KB (zero-padded s rows)

    const float* peb  = pe  + (size_t)b * (MM * RR);
    const int*   adjb = adj + (size_t)b * (PP * MM);

    // ---- stage: pe as float4 (240 vec4), kernels re-strided, adj -> float, idx, zero pads
    for (int i = t; i < (MM * RR) / 4; i += 256)
        *(float4*)&s_pe[i * 4] = *(const float4*)&peb[i * 4];
    for (int i = t; i < AA * FF; i += 256) {
        int a = (unsigned)i / FF, j = i - a * FF;
        s_kern[a * KS + j] = kernels[i];
    }
    for (int i = t; i < PP * MM; i += 256) {
        int p = (unsigned)i / MM, m = i - p * MM;
        s_adjf[p * AJ + m] = (float)adjb[i];
    }
    if (t < PP) s_idx[t] = idx[(size_t)b * PP + t];
    // zero the 20 pad slots per row: c<8 -> slot c ; c=8..19 -> slot 64+c (72..83)
    for (int i = t; i < PP * 20; i += 256) {
        int p = (unsigned)i / 20, c = i - p * 20;
        s_s[p * SP + (c < 8 ? c : 64 + c)] = 0.0f;
    }
    __syncthreads();

    // ---- Phase B: s[p][r0..r0+3] = sum_m adjf[p][m] * pe[m][r0..r0+3]   (544 float4 jobs)
    for (int i = t; i < PP * 16; i += 256) {
        const int p  = i >> 4;
        const int r0 = (i & 15) << 2;
        float ax = 0.f, ay = 0.f, az = 0.f, aw = 0.f;
        #pragma unroll
        for (int m = 0; m < MM; ++m) {
            const float g = s_adjf[p * AJ + m];
            const float4 v = *(const float4*)&s_pe[m * RR + r0];
            ax += g * v.x; ay += g * v.y; az += g * v.z; aw += g * v.w;
        }
        float4 acc; acc.x = ax; acc.y = ay; acc.z = az; acc.w = aw;
        *(float4*)&s_s[p * SP + 8 + r0] = acc;
    }
    __syncthreads();

    // ---- Phase C: out[p][o0..o0+3], fixed 9 taps, window of 12 floats via 3x b128 (612 jobs)
    float* outb = out + (size_t)b * (PP * OW);
    for (int i = t; i < PP * 18; i += 256) {
        const int p  = (unsigned)i / 18u;
        const int o0 = (i - p * 18) << 2;

        float w[12];
        {
            const float* base = &s_s[p * SP + o0];   // 16B-aligned (SP, o0 mult of 4)
            *(float4*)&w[0] = *(const float4*)&base[0];
            *(float4*)&w[4] = *(const float4*)&base[4];
            *(float4*)&w[8] = *(const float4*)&base[8];
        }
        float kf[KS];
        {
            const float* kb = &s_kern[s_idx[p] * KS]; // 16B-aligned
            *(float4*)&kf[0] = *(const float4*)&kb[0];
            *(float4*)&kf[4] = *(const float4*)&kb[4];
            kf[8] = kb[8];
        }
        float ax = 0.f, ay = 0.f, az = 0.f, aw = 0.f;
        #pragma unroll
        for (int j = 0; j < FF; ++j) {
            const float k = kf[j];
            // out[o0+c] += k * s[o0+c-j] = k * w[8+c-j]
            ax += k * w[8  - j];
            ay += k * w[9  - j];
            az += k * w[10 - j];
            aw += k * w[11 - j];
        }
        float4 acc; acc.x = ax; acc.y = ay; acc.z = az; acc.w = aw;
        *(float4*)&outb[p * OW + o0] = acc;          // 16B-aligned (OW*4=288B rows, o0 mult 4; block base 9792B)
    }
}

extern "C" void kernel_launch(void* const* d_in, const int* in_sizes, int n_in,
                              void* d_out, int out_size, void* d_ws, size_t ws_size,
                              hipStream_t stream) {
    const float* pe      = (const float*)d_in[0]; // [B,M,R] f32
    const int*   idx     = (const int*)  d_in[1]; // [B,P]   i32
    const int*   adj     = (const int*)  d_in[2]; // [B,P,M] i32
    const float* kernels = (const float*)d_in[3]; // [A,F]   f32
    float*       out     = (float*)d_out;

    const int B = in_sizes[0] / (MM * RR);
    ppc_kernel<<<B, 256, 0, stream>>>(pe, idx, adj, kernels, out);
}

// Round 8
// 78.000 us; speedup vs baseline: 1.3674x; 1.0110x over previous
//
#include <hip/hip_runtime.h>

// Problem constants
#define MM 15   // max_peptide_size
#define RR 64   // aa_rep_size
#define PP 34   // pocket positions
#define FF 9    // filter size
#define AA 20   // alphabet size
#define OW 72   // RR + FF - 1
#define SP 84   // padded s-row stride (floats), 16B-aligned
#define KS 12   // kernels row stride (floats), 16B-aligned
#define AJ 17   // adj-float row stride (bank-spread)
#define AJROWS 48  // 34 real rows + 14 zero rows so p=q+32 needs no branch

__global__ __launch_bounds__(256)
void ppc_kernel(const float* __restrict__ pe,      // [B, M, R]
                const int*   __restrict__ idx,     // [B, P]
                const int*   __restrict__ adj,     // [B, P, M]
                const float* __restrict__ kernels, // [A, F]
                float*       __restrict__ out)     // [B, P, OW]
{
    const int b = blockIdx.x;
    const int t = threadIdx.x;

    __shared__ float s_pe[MM * RR];        // 960 f
    __shared__ float s_kern[AA * KS];      // 240 f
    __shared__ float s_adjf[AJROWS * AJ];  // 816 f (rows >=34 zeroed)
    __shared__ int   s_idx[PP];
    __shared__ float s_s[PP * SP];         // 2856 f, zero-padded conv rows

    const float* peb  = pe  + (size_t)b * (MM * RR);
    const int*   adjb = adj + (size_t)b * (PP * MM);

    // ---- staging (coalesced)
    if (t < (MM * RR) / 4)
        *(float4*)&s_pe[t * 4] = *(const float4*)&peb[t * 4];
    for (int i = t; i < AA * FF; i += 256) {
        int a = (unsigned)i / FF, j = i - a * FF;
        s_kern[a * KS + j] = kernels[i];
    }
    for (int i = t; i < PP * MM; i += 256) {
        int p = (unsigned)i / MM, m = i - p * MM;
        s_adjf[p * AJ + m] = (float)adjb[i];
    }
    if (t < (AJROWS - PP) * AJ) s_adjf[PP * AJ + t] = 0.0f;   // 238 pad entries
    if (t < PP) s_idx[t] = idx[(size_t)b * PP + t];
    for (int i = t; i < PP * 20; i += 256) {                  // conv zero pads
        int p = (unsigned)i / 20, c = i - p * 20;
        s_s[p * SP + (c < 8 ? c : 64 + c)] = 0.0f;
    }
    __syncthreads();

    // ---- Phase B: thread (c,q) computes s[p][4c..4c+3] for p = q, q+16, q+32.
    // All q-groups in a wave read the SAME s_pe address per c -> LDS broadcast.
    {
        const int c  = t & 15;
        const int q  = t >> 4;
        const int r0 = c << 2;
        const float* g0 = &s_adjf[(q)      * AJ];
        const float* g1 = &s_adjf[(q + 16) * AJ];
        const float* g2 = &s_adjf[(q + 32) * AJ];   // zero row if q+32 >= 34
        float ax0=0,ay0=0,az0=0,aw0=0;
        float ax1=0,ay1=0,az1=0,aw1=0;
        float ax2=0,ay2=0,az2=0,aw2=0;
        #pragma unroll
        for (int m = 0; m < MM; ++m) {
            const float4 v = *(const float4*)&s_pe[m * RR + r0]; // broadcast read
            const float ga = g0[m], gb = g1[m], gc = g2[m];
            ax0 += ga * v.x; ay0 += ga * v.y; az0 += ga * v.z; aw0 += ga * v.w;
            ax1 += gb * v.x; ay1 += gb * v.y; az1 += gb * v.z; aw1 += gb * v.w;
            ax2 += gc * v.x; ay2 += gc * v.y; az2 += gc * v.z; aw2 += gc * v.w;
        }
        *(float4*)&s_s[(q)      * SP + 8 + r0] = make_float4(ax0, ay0, az0, aw0);
        *(float4*)&s_s[(q + 16) * SP + 8 + r0] = make_float4(ax1, ay1, az1, aw1);
        if (q + 32 < PP)
            *(float4*)&s_s[(q + 32) * SP + 8 + r0] = make_float4(ax2, ay2, az2, aw2);
    }
    __syncthreads();

    // ---- Phase C: out[p][o0..o0+3], fixed 9 taps, 12-float window via 3x b128
    float* outb = out + (size_t)b * (PP * OW);
    for (int i = t; i < PP * 18; i += 256) {
        const int p  = (unsigned)i / 18u;
        const int o0 = (i - p * 18) << 2;

        float w[12];
        {
            const float* base = &s_s[p * SP + o0];
            *(float4*)&w[0] = *(const float4*)&base[0];
            *(float4*)&w[4] = *(const float4*)&base[4];
            *(float4*)&w[8] = *(const float4*)&base[8];
        }
        float kf[KS];
        {
            const float* kb = &s_kern[s_idx[p] * KS];
            *(float4*)&kf[0] = *(const float4*)&kb[0];
            *(float4*)&kf[4] = *(const float4*)&kb[4];
            kf[8] = kb[8];
        }
        float ax = 0.f, ay = 0.f, az = 0.f, aw = 0.f;
        #pragma unroll
        for (int j = 0; j < FF; ++j) {
            const float k = kf[j];
            ax += k * w[8  - j];
            ay += k * w[9  - j];
            az += k * w[10 - j];
            aw += k * w[11 - j];
        }
        *(float4*)&outb[p * OW + o0] = make_float4(ax, ay, az, aw);
    }
}

extern "C" void kernel_launch(void* const* d_in, const int* in_sizes, int n_in,
                              void* d_out, int out_size, void* d_ws, size_t ws_size,
                              hipStream_t stream) {
    const float* pe      = (const float*)d_in[0]; // [B,M,R] f32
    const int*   idx     = (const int*)  d_in[1]; // [B,P]   i32
    const int*   adj     = (const int*)  d_in[2]; // [B,P,M] i32
    const float* kernels = (const float*)d_in[3]; // [A,F]   f32
    float*       out     = (float*)d_out;

    const int B = in_sizes[0] / (MM * RR);
    ppc_kernel<<<B, 256, 0, stream>>>(pe, idx, adj, kernels, out);
}